// Round 1
// baseline (971.998 us; speedup 1.0000x reference)
//
#include <hip/hip_runtime.h>
#include <hip/hip_bf16.h>

// NAM inference: h = clip((x-b)*exp(w),0,1); h2 = relu(h @ W1 + b1);
// logits = sum_f (h2 @ W2 + b2) + b_out; out = softmax(logits).
// B=2048, F=128, U=1024, V=512, C=10.

#define F_ 128
#define U_ 1024
#define V_ 512
#define C_ 10

#define SAB 72    // A/B staging LDS row stride (bf16): 64 + 8 pad, 144B (16B-aligned)
#define SH2 136   // h2 / W2T LDS row stride (bf16): 128 + 8 pad, 272B (16B-aligned)

typedef __attribute__((ext_vector_type(8))) short s16x8;
typedef __attribute__((ext_vector_type(4))) float fx4;

__device__ __forceinline__ unsigned bf16bits(float v) {
  unsigned u = __builtin_bit_cast(unsigned, v);
  return (u + 0x7fffu + ((u >> 16) & 1u)) >> 16;   // RNE, finite inputs only
}

__device__ __forceinline__ unsigned packbf16(float lo, float hi) {
#if __has_builtin(__builtin_amdgcn_cvt_pk_bf16_f32)
  typedef __attribute__((ext_vector_type(2))) __bf16 b2t;
  b2t p = __builtin_amdgcn_cvt_pk_bf16_f32(lo, hi);
  return __builtin_bit_cast(unsigned, p);
#else
  return bf16bits(lo) | (bf16bits(hi) << 16);
#endif
}

// Grid: 8192 blocks = f(128) x nb(4) x mb(16), mb innermost for W1-slice locality.
// Block: 256 thr = 4 waves, 2x2 over a 128x128 C-tile; wave = 64x64 via 4x4 MFMA frags.
__global__ __launch_bounds__(256, 2) void nam_main(
    const float* __restrict__ x, const float* __restrict__ exu_w,
    const float* __restrict__ exu_b, const float* __restrict__ W1,
    const float* __restrict__ b1, const float* __restrict__ W2,
    float* __restrict__ logits)
{
  __shared__ __attribute__((aligned(16))) char smem[45312];
  unsigned short* Alds = (unsigned short*)smem;             // [128][SAB] bf16 (18432 B)
  unsigned short* Blds = (unsigned short*)(smem + 18432);   // [128][SAB] bf16 (18432 B)
  unsigned short* H2   = (unsigned short*)smem;             // [128][SH2] bf16 (34816 B, reuses A+B)
  float*          eL   = (float*)(smem + 36864);            // [1024] exp(exu_w[f][:]) (4096 B)
  unsigned short* W2T  = (unsigned short*)(smem + 40960);   // [16][SH2] bf16, rows 10..15 zero

  const int bx = blockIdx.x;
  const int mb = bx & 15;
  const int nb = (bx >> 4) & 3;
  const int f  = bx >> 6;

  const int tid  = threadIdx.x;
  const int l    = tid & 63;
  const int w    = tid >> 6;
  const int wm   = (w >> 1) * 64;   // wave row-base in tile
  const int wn   = (w & 1) * 64;    // wave col-base in tile
  const int quad = l >> 4;
  const int ln16 = l & 15;

  // ---- exp table: e[u] = exp(exu_w[f][u]) ----
  {
    fx4 wv = *(const fx4*)(exu_w + (size_t)f * U_ + tid * 4);
    fx4 ev;
    ev.x = expf(wv.x); ev.y = expf(wv.y); ev.z = expf(wv.z); ev.w = expf(wv.w);
    *(fx4*)(eL + tid * 4) = ev;
  }

  // ---- per-thread staging params ----
  const float bfv  = exu_b[f];
  const int   mrow = tid >> 4;          // A staging: 8 rows {mrow+16j}
  const int   lk4  = (tid & 15) * 4;    // A staging: 4 consecutive k
  const int   aswz = (mrow & 7) * 8;    // XOR swizzle (function of row m&7)
  float d[8];
#pragma unroll
  for (int j = 0; j < 8; ++j)
    d[j] = x[(size_t)(mb * 128 + mrow + 16 * j) * F_ + f] - bfv;

  const int n4  = (tid & 31) * 4;       // B staging: 4 consecutive n (coalesced by lane)
  const int kb2 = (tid >> 5) * 2;       // B staging: k-pair base
  const float* w1b = W1 + (size_t)f * U_ * V_ + nb * 128 + n4;

  fx4 acc[4][4];
#pragma unroll
  for (int i = 0; i < 4; ++i)
#pragma unroll
    for (int j = 0; j < 4; ++j)
      acc[i][j] = fx4{0.f, 0.f, 0.f, 0.f};

  __syncthreads();  // eL ready

  for (int kt = 0; kt < 16; ++kt) {
    // ---- stage A: h[m][k] = clip(d_m * e_k, 0, 1), layout [m][k^swz(m)] ----
    fx4 ev = *(const fx4*)(eL + kt * 64 + lk4);
#pragma unroll
    for (int j = 0; j < 8; ++j) {
      const int m = mrow + 16 * j;
      float h0 = fminf(fmaxf(d[j] * ev.x, 0.f), 1.f);
      float h1 = fminf(fmaxf(d[j] * ev.y, 0.f), 1.f);
      float h2 = fminf(fmaxf(d[j] * ev.z, 0.f), 1.f);
      float h3 = fminf(fmaxf(d[j] * ev.w, 0.f), 1.f);
      uint2 pk;
      pk.x = packbf16(h0, h1);
      pk.y = packbf16(h2, h3);
      *(uint2*)(Alds + m * SAB + (lk4 ^ aswz)) = pk;   // 8B store, aligned
    }
    // ---- stage B: W1[u][v] -> Blds[n=v][k=u] (transpose via k-row pairs) ----
#pragma unroll
    for (int r = 0; r < 4; ++r) {
      const int k0 = kb2 + 16 * r;
      fx4 r0 = *(const fx4*)(w1b + (size_t)(kt * 64 + k0) * V_);
      fx4 r1 = *(const fx4*)(w1b + (size_t)(kt * 64 + k0 + 1) * V_);
#pragma unroll
      for (int c = 0; c < 4; ++c) {
        const int n = n4 + c;
        unsigned dw = packbf16(r0[c], r1[c]);          // (k0, k0+1) bf16 pair
        *(unsigned*)(Blds + n * SAB + (k0 ^ (((n >> 2) & 7) * 8))) = dw;
      }
    }
    __syncthreads();

    // ---- MFMA: 2 k-steps of 32 ----
#pragma unroll
    for (int kk = 0; kk < 2; ++kk) {
      const int k0 = kk * 32 + quad * 8;
      s16x8 af[4], bfr[4];
#pragma unroll
      for (int i = 0; i < 4; ++i) {
        const int m = wm + i * 16 + ln16;
        af[i] = *(const s16x8*)(Alds + m * SAB + (k0 ^ ((m & 7) * 8)));
      }
#pragma unroll
      for (int j = 0; j < 4; ++j) {
        const int n = wn + j * 16 + ln16;
        bfr[j] = *(const s16x8*)(Blds + n * SAB + (k0 ^ (((n >> 2) & 7) * 8)));
      }
#pragma unroll
      for (int i = 0; i < 4; ++i)
#pragma unroll
        for (int j = 0; j < 4; ++j)
          acc[i][j] = __builtin_amdgcn_mfma_f32_16x16x32_bf16(af[i], bfr[j], acc[i][j], 0, 0, 0);
    }
    __syncthreads();
  }

  // ---- epilogue: fused GEMM2 into logits ----
  // stage W2 slice transposed: W2T[c][v] = W2[f][nb*128+v][c], rows 10..15 zero
#pragma unroll
  for (int it = 0; it < 8; ++it) {
    const int idx = tid + it * 256;     // 0..2047 = 16c x 128v
    const int c = idx & 15, v = idx >> 4;
    float val = (c < C_) ? W2[((size_t)f * V_ + nb * 128 + v) * C_ + c] : 0.f;
    W2T[c * SH2 + v] = (unsigned short)bf16bits(val);
  }

  // h2 = relu(acc + b1) -> bf16 LDS tile [m][v]
#pragma unroll
  for (int j = 0; j < 4; ++j) {
    const int n = wn + j * 16 + ln16;
    const float b1v = b1[(size_t)f * V_ + nb * 128 + n];
#pragma unroll
    for (int i = 0; i < 4; ++i)
#pragma unroll
      for (int reg = 0; reg < 4; ++reg) {
        const int m = wm + i * 16 + quad * 4 + reg;   // C/D layout: row=(l>>4)*4+reg, col=l&15
        float v = fmaxf(acc[i][j][reg] + b1v, 0.f);
        H2[m * SH2 + n] = (unsigned short)bf16bits(v);
      }
  }
  __syncthreads();

  // GEMM2: [128m x 128v] x [128v x 16c]; waves: wm = m-half, wn reused as k-half
  fx4 acc2[4];
#pragma unroll
  for (int i = 0; i < 4; ++i) acc2[i] = fx4{0.f, 0.f, 0.f, 0.f};

  const int kj = wn;
#pragma unroll
  for (int kk = 0; kk < 2; ++kk) {
    const int k0 = kj + kk * 32 + quad * 8;
    s16x8 bfr = *(const s16x8*)(W2T + ln16 * SH2 + k0);
#pragma unroll
    for (int i = 0; i < 4; ++i) {
      const int m = wm + i * 16 + ln16;
      s16x8 afr = *(const s16x8*)(H2 + m * SH2 + k0);
      acc2[i] = __builtin_amdgcn_mfma_f32_16x16x32_bf16(afr, bfr, acc2[i], 0, 0, 0);
    }
  }

  if (ln16 < C_) {
#pragma unroll
    for (int i = 0; i < 4; ++i)
#pragma unroll
      for (int reg = 0; reg < 4; ++reg) {
        const int m = mb * 128 + wm + i * 16 + quad * 4 + reg;
        atomicAdd(logits + (size_t)m * C_ + ln16, acc2[i][reg]);
      }
  }
}

// blocks 0..79: zero logits[2048*10]; block 80: biasc[c] = b_out[c] + sum_f b2[f][c]
__global__ void nam_zero(const float* __restrict__ b2, const float* __restrict__ b_out,
                         float* __restrict__ logits, float* __restrict__ biasc)
{
  const int bid = blockIdx.x, tid = threadIdx.x;
  if (bid < 80) {
    logits[bid * 256 + tid] = 0.f;
  } else if (tid < C_) {
    float s = b_out[tid];
    for (int ff = 0; ff < F_; ++ff) s += b2[ff * C_ + tid];
    biasc[tid] = s;
  }
}

__global__ void nam_softmax(const float* __restrict__ logits, const float* __restrict__ biasc,
                            float* __restrict__ out)
{
  const int row = blockIdx.x * 256 + threadIdx.x;   // 2048 rows
  float v[C_];
  float mx = -3.0e38f;
#pragma unroll
  for (int c = 0; c < C_; ++c) {
    v[c] = logits[(size_t)row * C_ + c] + biasc[c];
    mx = fmaxf(mx, v[c]);
  }
  float s = 0.f;
#pragma unroll
  for (int c = 0; c < C_; ++c) { v[c] = expf(v[c] - mx); s += v[c]; }
  const float inv = 1.f / s;
#pragma unroll
  for (int c = 0; c < C_; ++c) out[(size_t)row * C_ + c] = v[c] * inv;
}

extern "C" void kernel_launch(void* const* d_in, const int* in_sizes, int n_in,
                              void* d_out, int out_size, void* d_ws, size_t ws_size,
                              hipStream_t stream)
{
  const float* x     = (const float*)d_in[0];
  const float* exu_w = (const float*)d_in[1];
  const float* exu_b = (const float*)d_in[2];
  const float* W1    = (const float*)d_in[3];
  const float* b1    = (const float*)d_in[4];
  const float* W2    = (const float*)d_in[5];
  const float* b2    = (const float*)d_in[6];
  const float* b_out = (const float*)d_in[7];
  float* out    = (float*)d_out;
  float* logits = (float*)d_ws;                       // 2048*10 f32 = 81920 B
  float* biasc  = (float*)((char*)d_ws + 2048 * C_ * sizeof(float));  // 10 f32

  nam_zero<<<81, 256, 0, stream>>>(b2, b_out, logits, biasc);
  nam_main<<<8192, 256, 0, stream>>>(x, exu_w, exu_b, W1, b1, W2, logits);
  nam_softmax<<<8, 256, 0, stream>>>(logits, biasc, out);
}

// Round 2
// 422.019 us; speedup vs baseline: 2.3032x; 2.3032x over previous
//
#include <hip/hip_runtime.h>
#include <hip/hip_bf16.h>

// NAM inference, structure-exploiting version.
// h = clip(d * e_u, 0, 1) with d = x[b,f]-exu_b[f], e_u = exp(exu_w[f,u]) > 0.
//   d <= 0          -> h row all 0 -> h2 = relu(b1)            (per-f constant)
//   d*emin_f >= 1   -> h row all 1 -> h2 = relu(colsum1 + b1)  (per-f constant, EXACT)
//   else ("middle") -> real GEMM row (~3.5% of pairs for N(0,1) inputs)
// Pipeline: prep -> classify(build lists) -> fused colsum+middle-MFMA-GEMM ->
//           per-f class tables -> per-row gather + softmax.
// B=2048, F=128, U=1024, V=512, C=10.

#define F_ 128
#define U_ 1024
#define V_ 512
#define C_ 10
#define B_ 2048

#define SAB 72    // A/B staging LDS row stride (bf16): 64 + 8 pad
#define SH2 136   // h2 / W2T LDS row stride (bf16): 128 + 8 pad

typedef __attribute__((ext_vector_type(8))) short s16x8;
typedef __attribute__((ext_vector_type(4))) float fx4;

__device__ __forceinline__ unsigned bf16bits(float v) {
  unsigned u = __builtin_bit_cast(unsigned, v);
  return (u + 0x7fffu + ((u >> 16) & 1u)) >> 16;   // RNE, finite inputs only
}

__device__ __forceinline__ unsigned packbf16(float lo, float hi) {
#if __has_builtin(__builtin_amdgcn_cvt_pk_bf16_f32)
  typedef __attribute__((ext_vector_type(2))) __bf16 b2t;
  b2t p = __builtin_amdgcn_cvt_pk_bf16_f32(lo, hi);
  return __builtin_bit_cast(unsigned, p);
#else
  return bf16bits(lo) | (bf16bits(hi) << 16);
#endif
}

// ---------------- K1: emin per feature, biasc, zero counters/logits_mid ----------------
__global__ void nam_prep(const float* __restrict__ exu_w, const float* __restrict__ b2,
                         const float* __restrict__ b_out,
                         float* __restrict__ emin, float* __restrict__ biasc,
                         int* __restrict__ count, float* __restrict__ logits_mid)
{
  __shared__ float red[256];
  const int bid = blockIdx.x, t = threadIdx.x;
  if (bid < F_) {
    fx4 wv = *(const fx4*)(exu_w + (size_t)bid * U_ + t * 4);
    float m = fminf(fminf(expf(wv.x), expf(wv.y)), fminf(expf(wv.z), expf(wv.w)));
    red[t] = m;
    __syncthreads();
    for (int s = 128; s > 0; s >>= 1) {
      if (t < s) red[t] = fminf(red[t], red[t + s]);
      __syncthreads();
    }
    if (t == 0) emin[bid] = red[0];
  } else if (bid == F_) {
    if (t < C_) {
      float s = b_out[t];
      for (int ff = 0; ff < F_; ++ff) s += b2[ff * C_ + t];
      biasc[t] = s;
    } else if (t >= 32 && t < 32 + F_) {
      count[t - 32] = 0;
    }
  } else {
    const int idx = (bid - F_ - 1) * 256 + t;   // 80 blocks -> 20480 = B_*C_
    logits_mid[idx] = 0.f;
  }
}

// ---------------- K2: classify, build per-feature middle-row lists ----------------
__global__ void nam_classify(const float* __restrict__ x, const float* __restrict__ exu_b,
                             const float* __restrict__ emin,
                             int* __restrict__ count, int* __restrict__ listb)
{
  const int t = threadIdx.x;
  const int f = t & 127, sub = t >> 7;
  const int b = blockIdx.x * 2 + sub;
  const float d = x[(size_t)b * F_ + f] - exu_b[f];
  if (d > 0.f && d * emin[f] < 1.f) {
    const int idx = atomicAdd(count + f, 1);
    listb[f * B_ + idx] = b;
  }
}

// ---------------- K3: fused colsum(W1) + middle-row MFMA GEMM ----------------
// Grid: 512 = f(128) x nb(4). Block: 256 thr, round-1 tile structure (128x128).
__global__ __launch_bounds__(256, 2) void nam_mid(
    const float* __restrict__ x, const float* __restrict__ exu_w,
    const float* __restrict__ exu_b, const float* __restrict__ W1,
    const float* __restrict__ b1, const float* __restrict__ W2,
    const int* __restrict__ listb, const int* __restrict__ count,
    float* __restrict__ colsum1, float* __restrict__ logits_mid)
{
  __shared__ __attribute__((aligned(16))) char smem[49408];
  unsigned short* Alds = (unsigned short*)smem;             // [128][SAB]
  unsigned short* Blds = (unsigned short*)(smem + 18432);   // [128][SAB]
  unsigned short* H2   = (unsigned short*)smem;             // [128][SH2] overlays A+B
  float*          eL   = (float*)(smem + 36864);            // [1024] exp table
  unsigned short* W2T  = (unsigned short*)(smem + 40960);   // [16][SH2]
  float*          rsum = (float*)(smem + 45312);            // [8][128] colsum partials

  const int bx = blockIdx.x;
  const int nb = bx & 3;
  const int f  = bx >> 2;

  const int tid  = threadIdx.x;
  const int l    = tid & 63;
  const int w    = tid >> 6;
  const int wm   = (w >> 1) * 64;
  const int wn   = (w & 1) * 64;
  const int quad = l >> 4;
  const int ln16 = l & 15;

  // exp table for this feature
  {
    fx4 wv = *(const fx4*)(exu_w + (size_t)f * U_ + tid * 4);
    fx4 ev;
    ev.x = expf(wv.x); ev.y = expf(wv.y); ev.z = expf(wv.z); ev.w = expf(wv.w);
    *(fx4*)(eL + tid * 4) = ev;
  }
  // W2 slice transposed (rows 10..15 zero)
#pragma unroll
  for (int it = 0; it < 8; ++it) {
    const int idx = tid + it * 256;
    const int c = idx & 15, v = idx >> 4;
    float val = (c < C_) ? W2[((size_t)f * V_ + nb * 128 + v) * C_ + c] : 0.f;
    W2T[c * SH2 + v] = (unsigned short)bf16bits(val);
  }

  const int   nmid = count[f];
  const float bfv  = exu_b[f];

  const int mrow = tid >> 4;
  const int lk4  = (tid & 15) * 4;
  const int aswz = (mrow & 7) * 8;

  const int n4  = (tid & 31) * 4;
  const int kb2 = (tid >> 5) * 2;
  const float* w1b = W1 + (size_t)f * U_ * V_ + nb * 128 + n4;

  float csum[4] = {0.f, 0.f, 0.f, 0.f};
  const int nchunk = nmid > 0 ? ((nmid + 127) >> 7) : 1;

  __syncthreads();  // eL, W2T ready

  for (int ch = 0; ch < nchunk; ++ch) {
    // gather d for this chunk's rows (padding rows: d=0 -> h row = 0)
    float d[8];
#pragma unroll
    for (int j = 0; j < 8; ++j) {
      const int gi = ch * 128 + mrow + 16 * j;
      if (gi < nmid) {
        const int bb = listb[f * B_ + gi];
        d[j] = x[(size_t)bb * F_ + f] - bfv;
      } else {
        d[j] = 0.f;
      }
    }

    fx4 acc[4][4];
#pragma unroll
    for (int i = 0; i < 4; ++i)
#pragma unroll
      for (int j = 0; j < 4; ++j)
        acc[i][j] = fx4{0.f, 0.f, 0.f, 0.f};

    for (int kt = 0; kt < 16; ++kt) {
      // stage A: h rows for gathered b's
      fx4 ev = *(const fx4*)(eL + kt * 64 + lk4);
#pragma unroll
      for (int j = 0; j < 8; ++j) {
        const int m = mrow + 16 * j;
        float h0 = fminf(fmaxf(d[j] * ev.x, 0.f), 1.f);
        float h1 = fminf(fmaxf(d[j] * ev.y, 0.f), 1.f);
        float h2 = fminf(fmaxf(d[j] * ev.z, 0.f), 1.f);
        float h3 = fminf(fmaxf(d[j] * ev.w, 0.f), 1.f);
        uint2 pk;
        pk.x = packbf16(h0, h1);
        pk.y = packbf16(h2, h3);
        *(uint2*)(Alds + m * SAB + (lk4 ^ aswz)) = pk;
      }
      // stage B: W1[u][v] -> Blds[n=v][k=u]; fused colsum accumulation (chunk 0 only)
#pragma unroll
      for (int r = 0; r < 4; ++r) {
        const int k0 = kb2 + 16 * r;
        fx4 r0 = *(const fx4*)(w1b + (size_t)(kt * 64 + k0) * V_);
        fx4 r1 = *(const fx4*)(w1b + (size_t)(kt * 64 + k0 + 1) * V_);
        if (ch == 0) {
#pragma unroll
          for (int c = 0; c < 4; ++c) csum[c] += r0[c] + r1[c];
        }
#pragma unroll
        for (int c = 0; c < 4; ++c) {
          const int n = n4 + c;
          unsigned dw = packbf16(r0[c], r1[c]);
          *(unsigned*)(Blds + n * SAB + (k0 ^ (((n >> 2) & 7) * 8))) = dw;
        }
      }
      __syncthreads();

#pragma unroll
      for (int kk = 0; kk < 2; ++kk) {
        const int k0 = kk * 32 + quad * 8;
        s16x8 af[4], bfr[4];
#pragma unroll
        for (int i = 0; i < 4; ++i) {
          const int m = wm + i * 16 + ln16;
          af[i] = *(const s16x8*)(Alds + m * SAB + (k0 ^ ((m & 7) * 8)));
        }
#pragma unroll
        for (int j = 0; j < 4; ++j) {
          const int n = wn + j * 16 + ln16;
          bfr[j] = *(const s16x8*)(Blds + n * SAB + (k0 ^ (((n >> 2) & 7) * 8)));
        }
#pragma unroll
        for (int i = 0; i < 4; ++i)
#pragma unroll
          for (int j = 0; j < 4; ++j)
            acc[i][j] = __builtin_amdgcn_mfma_f32_16x16x32_bf16(af[i], bfr[j], acc[i][j], 0, 0, 0);
      }
      __syncthreads();
    }

    // colsum reduce+write (once)
    if (ch == 0) {
      rsum[(tid >> 5) * 128 + n4 + 0] = csum[0];
      rsum[(tid >> 5) * 128 + n4 + 1] = csum[1];
      rsum[(tid >> 5) * 128 + n4 + 2] = csum[2];
      rsum[(tid >> 5) * 128 + n4 + 3] = csum[3];
      __syncthreads();
      if (tid < 128) {
        float s = 0.f;
#pragma unroll
        for (int g = 0; g < 8; ++g) s += rsum[g * 128 + tid];
        colsum1[(size_t)f * V_ + nb * 128 + tid] = s;
      }
    }

    // epilogue: h2 = relu(acc + b1) -> H2, then GEMM2 vs W2T, masked atomic add
#pragma unroll
    for (int j = 0; j < 4; ++j) {
      const int n = wn + j * 16 + ln16;
      const float b1v = b1[(size_t)f * V_ + nb * 128 + n];
#pragma unroll
      for (int i = 0; i < 4; ++i)
#pragma unroll
        for (int reg = 0; reg < 4; ++reg) {
          const int m = wm + i * 16 + quad * 4 + reg;
          float v = fmaxf(acc[i][j][reg] + b1v, 0.f);
          H2[m * SH2 + n] = (unsigned short)bf16bits(v);
        }
    }
    __syncthreads();

    fx4 acc2[4];
#pragma unroll
    for (int i = 0; i < 4; ++i) acc2[i] = fx4{0.f, 0.f, 0.f, 0.f};
    const int kj = wn;
#pragma unroll
    for (int kk = 0; kk < 2; ++kk) {
      const int k0 = kj + kk * 32 + quad * 8;
      s16x8 bfr = *(const s16x8*)(W2T + ln16 * SH2 + k0);
#pragma unroll
      for (int i = 0; i < 4; ++i) {
        const int m = wm + i * 16 + ln16;
        s16x8 afr = *(const s16x8*)(H2 + m * SH2 + k0);
        acc2[i] = __builtin_amdgcn_mfma_f32_16x16x32_bf16(afr, bfr, acc2[i], 0, 0, 0);
      }
    }

    if (ln16 < C_) {
#pragma unroll
      for (int i = 0; i < 4; ++i)
#pragma unroll
        for (int reg = 0; reg < 4; ++reg) {
          const int ml = wm + i * 16 + quad * 4 + reg;
          const int gm = ch * 128 + ml;
          if (gm < nmid) {
            const int bb = listb[f * B_ + gm];
            atomicAdd(logits_mid + (size_t)bb * C_ + ln16, acc2[i][reg]);
          }
        }
    }
    __syncthreads();  // before next chunk re-stages A/B over H2
  }
}

// ---------------- K4: per-feature zero/one class tables ----------------
__global__ void nam_tables(const float* __restrict__ colsum1, const float* __restrict__ b1,
                           const float* __restrict__ W2,
                           float* __restrict__ zlog, float* __restrict__ olog)
{
  const int f = blockIdx.x, t = threadIdx.x;
  float a0[C_], a1[C_];
#pragma unroll
  for (int c = 0; c < C_; ++c) { a0[c] = 0.f; a1[c] = 0.f; }
#pragma unroll
  for (int rep = 0; rep < 2; ++rep) {
    const int v = t + rep * 256;
    const float b1v = b1[(size_t)f * V_ + v];
    const float hz = fmaxf(b1v, 0.f);
    const float ho = fmaxf(colsum1[(size_t)f * V_ + v] + b1v, 0.f);
    const float* w2p = W2 + ((size_t)f * V_ + v) * C_;
#pragma unroll
    for (int c = 0; c < C_; ++c) {
      const float wv = w2p[c];
      a0[c] += hz * wv;
      a1[c] += ho * wv;
    }
  }
#pragma unroll
  for (int off = 32; off > 0; off >>= 1)
#pragma unroll
    for (int c = 0; c < C_; ++c) {
      a0[c] += __shfl_down(a0[c], off);
      a1[c] += __shfl_down(a1[c], off);
    }
  __shared__ float red[4][2 * C_];
  const int wv_ = t >> 6, ln = t & 63;
  if (ln == 0)
#pragma unroll
    for (int c = 0; c < C_; ++c) { red[wv_][c] = a0[c]; red[wv_][C_ + c] = a1[c]; }
  __syncthreads();
  if (t < 2 * C_) {
    const float s = red[0][t] + red[1][t] + red[2][t] + red[3][t];
    if (t < C_) zlog[t * F_ + f] = s;
    else        olog[(t - C_) * F_ + f] = s;
  }
}

// ---------------- K5: gather per-row contributions + softmax ----------------
__global__ void nam_final(const float* __restrict__ x, const float* __restrict__ exu_b,
                          const float* __restrict__ emin,
                          const float* __restrict__ zlog, const float* __restrict__ olog,
                          const float* __restrict__ biasc, const float* __restrict__ logits_mid,
                          float* __restrict__ out)
{
  const int t = threadIdx.x;
  const int f = t & 127, sub = t >> 7;
  const int b = blockIdx.x * 2 + sub;
  const float d  = x[(size_t)b * F_ + f] - exu_b[f];
  const float em = emin[f];
  const bool is_zero = !(d > 0.f);
  const bool is_one  = (d > 0.f) && (d * em >= 1.f);
  float a[C_];
#pragma unroll
  for (int c = 0; c < C_; ++c) {
    const float zv = zlog[c * F_ + f];
    const float ov = olog[c * F_ + f];
    a[c] = is_zero ? zv : (is_one ? ov : 0.f);
  }
#pragma unroll
  for (int off = 32; off > 0; off >>= 1)
#pragma unroll
    for (int c = 0; c < C_; ++c) a[c] += __shfl_down(a[c], off);
  __shared__ float red[4][C_];
  __shared__ float lg[2][C_];
  const int wv_ = t >> 6, ln = t & 63;
  if (ln == 0)
#pragma unroll
    for (int c = 0; c < C_; ++c) red[wv_][c] = a[c];
  __syncthreads();
  if (t < 2 * C_) {
    const int rb = t / C_, c = t % C_;
    lg[rb][c] = red[rb * 2][c] + red[rb * 2 + 1][c]
              + logits_mid[(size_t)(blockIdx.x * 2 + rb) * C_ + c] + biasc[c];
  }
  __syncthreads();
  if (t < 2) {
    float mx = -3.0e38f;
#pragma unroll
    for (int c = 0; c < C_; ++c) mx = fmaxf(mx, lg[t][c]);
    float e[C_];
    float s = 0.f;
#pragma unroll
    for (int c = 0; c < C_; ++c) { e[c] = expf(lg[t][c] - mx); s += e[c]; }
    const float inv = 1.f / s;
#pragma unroll
    for (int c = 0; c < C_; ++c) out[(size_t)(blockIdx.x * 2 + t) * C_ + c] = e[c] * inv;
  }
}

extern "C" void kernel_launch(void* const* d_in, const int* in_sizes, int n_in,
                              void* d_out, int out_size, void* d_ws, size_t ws_size,
                              hipStream_t stream)
{
  const float* x     = (const float*)d_in[0];
  const float* exu_w = (const float*)d_in[1];
  const float* exu_b = (const float*)d_in[2];
  const float* W1    = (const float*)d_in[3];
  const float* b1    = (const float*)d_in[4];
  const float* W2    = (const float*)d_in[5];
  const float* b2    = (const float*)d_in[6];
  const float* b_out = (const float*)d_in[7];
  float* out = (float*)d_out;

  char* ws = (char*)d_ws;
  float* emin       = (float*)(ws + 0);                 //   512 B
  float* biasc      = (float*)(ws + 512);               //    40 B (pad to 576)
  int*   count      = (int*)  (ws + 576);               //   512 B
  int*   listb      = (int*)  (ws + 1088);              // 1 MB (128*2048*4)
  float* colsum1    = (float*)(ws + 1049664);           // 256 KB
  float* zlog       = (float*)(ws + 1311808);           //  5 KB
  float* olog       = (float*)(ws + 1316928);           //  5 KB
  float* logits_mid = (float*)(ws + 1322048);           // 80 KB -> ends 1403968

  nam_prep<<<F_ + 1 + (B_ * C_ / 256), 256, 0, stream>>>(exu_w, b2, b_out, emin, biasc, count, logits_mid);
  nam_classify<<<B_ / 2, 256, 0, stream>>>(x, exu_b, emin, count, listb);
  nam_mid<<<F_ * 4, 256, 0, stream>>>(x, exu_w, exu_b, W1, b1, W2, listb, count, colsum1, logits_mid);
  nam_tables<<<F_, 256, 0, stream>>>(colsum1, b1, W2, zlog, olog);
  nam_final<<<B_ / 2, 256, 0, stream>>>(x, exu_b, emin, zlog, olog, biasc, logits_mid, out);
}

// Round 3
// 416.033 us; speedup vs baseline: 2.3363x; 1.0144x over previous
//
#include <hip/hip_runtime.h>
#include <hip/hip_bf16.h>

// NAM inference, structure-exploiting + pipelined-stream version.
// h = clip(d * e_u, 0, 1), d = x[b,f]-exu_b[f], e_u = exp(exu_w[f,u]) > 0.
//   d <= 0        -> h row all 0 -> h2 = relu(b1)            (per-f constant)
//   d*emin_f >= 1 -> h row all 1 -> h2 = relu(colsum1 + b1)  (per-f constant, EXACT)
//   else          -> real GEMM row (~3.5% of pairs)
// K3 (nam_mid) streams W1 once (268 MB, the structural floor): double-buffered
// LDS + VGPR prefetch, ONE barrier per k-tile; fused colsum + middle-row MFMA
// GEMM + per-feature zero/one class tables in the epilogue.
// B=2048, F=128, U=1024, V=512, C=10.

#define F_ 128
#define U_ 1024
#define V_ 512
#define C_ 10
#define B_ 2048

#define SAB 72    // A/B staging LDS row stride (bf16): 64 + 8 pad
#define SH2 136   // h2 / W2T LDS row stride (bf16): 128 + 8 pad

typedef __attribute__((ext_vector_type(8))) short s16x8;
typedef __attribute__((ext_vector_type(4))) float fx4;

__device__ __forceinline__ unsigned bf16bits(float v) {
  unsigned u = __builtin_bit_cast(unsigned, v);
  return (u + 0x7fffu + ((u >> 16) & 1u)) >> 16;   // RNE, finite inputs only
}

__device__ __forceinline__ unsigned packbf16(float lo, float hi) {
#if __has_builtin(__builtin_amdgcn_cvt_pk_bf16_f32)
  typedef __attribute__((ext_vector_type(2))) __bf16 b2t;
  b2t p = __builtin_amdgcn_cvt_pk_bf16_f32(lo, hi);
  return __builtin_bit_cast(unsigned, p);
#else
  return bf16bits(lo) | (bf16bits(hi) << 16);
#endif
}

// ---------------- K1: emin, biasc, zero count/logits_mid/zlog/olog ----------------
__global__ void nam_prep(const float* __restrict__ exu_w, const float* __restrict__ b2,
                         const float* __restrict__ b_out,
                         float* __restrict__ emin, float* __restrict__ biasc,
                         int* __restrict__ count, float* __restrict__ logits_mid,
                         float* __restrict__ zlog, float* __restrict__ olog)
{
  __shared__ float red[256];
  const int bid = blockIdx.x, t = threadIdx.x;
  if (bid < F_) {
    fx4 wv = *(const fx4*)(exu_w + (size_t)bid * U_ + t * 4);
    red[t] = fminf(fminf(wv.x, wv.y), fminf(wv.z, wv.w));
    __syncthreads();
    for (int s = 128; s > 0; s >>= 1) {
      if (t < s) red[t] = fminf(red[t], red[t + s]);
      __syncthreads();
    }
    if (t == 0) emin[bid] = expf(red[0]);   // exp monotone: min(exp(w)) = exp(min w)
  } else if (bid == F_) {
    if (t < C_) {
      float s = b_out[t];
      for (int ff = 0; ff < F_; ++ff) s += b2[ff * C_ + t];
      biasc[t] = s;
    } else if (t >= 32 && t < 32 + F_) {
      count[t - 32] = 0;
    }
    for (int i = t; i < C_ * F_; i += 256) { zlog[i] = 0.f; olog[i] = 0.f; }
  } else {
    const int idx = (bid - F_ - 1) * 256 + t;   // 80 blocks -> 20480 = B_*C_
    logits_mid[idx] = 0.f;
  }
}

// ---------------- K2: classify rows, build per-feature middle lists ----------------
__global__ void nam_classify(const float* __restrict__ x, const float* __restrict__ exu_b,
                             const float* __restrict__ emin,
                             int* __restrict__ count, int* __restrict__ listb)
{
  const int t = threadIdx.x;
  const int f = t & 127, sub = t >> 7;
  const int b = blockIdx.x * 2 + sub;
  const float d = x[(size_t)b * F_ + f] - exu_b[f];
  if (d > 0.f && d * emin[f] < 1.f) {
    const int idx = atomicAdd(count + f, 1);
    listb[f * B_ + idx] = b;
  }
}

// ---------------- K3: streamed colsum(W1) + middle MFMA GEMM + tables ----------------
// Grid: 512 = f(128) x nb(4). Block: 256 thr, 128x128 tile, dbuf LDS, 1 barrier/kt.
__global__ __launch_bounds__(256, 2) void nam_mid(
    const float* __restrict__ x, const float* __restrict__ exu_w,
    const float* __restrict__ exu_b, const float* __restrict__ W1,
    const float* __restrict__ b1, const float* __restrict__ W2,
    const int* __restrict__ listb, const int* __restrict__ count,
    float* __restrict__ colsum1, float* __restrict__ logits_mid,
    float* __restrict__ zlog, float* __restrict__ olog)
{
  __shared__ __attribute__((aligned(16))) char smem[77824];
  unsigned short* A0  = (unsigned short*)smem;               //  0..18432
  unsigned short* B0  = (unsigned short*)(smem + 18432);     //  ..36864
  unsigned short* A1  = (unsigned short*)(smem + 36864);     //  ..55296
  unsigned short* B1  = (unsigned short*)(smem + 55296);     //  ..73728
  unsigned short* H2  = (unsigned short*)smem;               // [128][SH2] = 34816 (epilogue, over A0+B0)
  unsigned short* W2T = (unsigned short*)(smem + 36864);     // [16][SH2] = 4352 (epilogue, over A1)
  float*          rsum= (float*)(smem + 41216);              // [8][128] (epilogue, over A1)
  float*          redt= (float*)(smem + 45312);              // [2][20]  (epilogue, over A1)
  float*          eL  = (float*)(smem + 73728);              // [1024] exp table

  const int bx = blockIdx.x;
  const int nb = bx & 3;
  const int f  = bx >> 2;

  const int tid  = threadIdx.x;
  const int l    = tid & 63;
  const int w    = tid >> 6;
  const int wm   = (w >> 1) * 64;
  const int wn   = (w & 1) * 64;
  const int quad = l >> 4;
  const int ln16 = l & 15;

  // exp table for this feature
  {
    fx4 wv = *(const fx4*)(exu_w + (size_t)f * U_ + tid * 4);
    fx4 ev;
    ev.x = expf(wv.x); ev.y = expf(wv.y); ev.z = expf(wv.z); ev.w = expf(wv.w);
    *(fx4*)(eL + tid * 4) = ev;
  }

  const int   nmid = count[f];
  const float bfv  = exu_b[f];

  // A-staging mapping
  const int mrow = tid >> 4;            // 8 rows {mrow+16j}
  const int lk4  = (tid & 15) * 4;      // 4 consecutive k
  const int aswz = (mrow & 7) * 8;

  // B-staging mapping (k-quad packing, b64 writes)
  const int c    = tid & 31;            // v-group
  const int n4   = c * 4;
  const int kq   = tid >> 5;            // 0..7
  const int bswz = (c & 7) * 8;
  const float* w1b = W1 + (size_t)f * U_ * V_ + nb * 128 + n4;

  float csum[4] = {0.f, 0.f, 0.f, 0.f};
  const int nchunk = nmid > 0 ? ((nmid + 127) >> 7) : 1;

  fx4 pre0[8], pre1[8];

#define ISSUE_B(pre, kt)                                                        \
  {                                                                             \
    _Pragma("unroll")                                                           \
    for (int r = 0; r < 2; ++r)                                                 \
      _Pragma("unroll")                                                         \
      for (int i = 0; i < 4; ++i)                                               \
        pre[r * 4 + i] = *(const fx4*)(w1b + (size_t)((kt) * 64 + kq * 4 + r * 32 + i) * V_); \
  }

#define PACK_B(pre, Bb, do_sum)                                                 \
  {                                                                             \
    _Pragma("unroll")                                                           \
    for (int r = 0; r < 2; ++r) {                                               \
      const int k0 = kq * 4 + r * 32;                                           \
      if (do_sum) {                                                             \
        _Pragma("unroll")                                                       \
        for (int c2 = 0; c2 < 4; ++c2)                                          \
          csum[c2] += pre[r*4+0][c2] + pre[r*4+1][c2] + pre[r*4+2][c2] + pre[r*4+3][c2]; \
      }                                                                         \
      _Pragma("unroll")                                                         \
      for (int c2 = 0; c2 < 4; ++c2) {                                          \
        uint2 pk;                                                               \
        pk.x = packbf16(pre[r*4+0][c2], pre[r*4+1][c2]);                        \
        pk.y = packbf16(pre[r*4+2][c2], pre[r*4+3][c2]);                        \
        *(uint2*)(Bb + (n4 + c2) * SAB + (k0 ^ bswz)) = pk;                     \
      }                                                                         \
    }                                                                           \
  }

#define STAGE_A(kt, Ab)                                                         \
  {                                                                             \
    fx4 ev = *(const fx4*)(eL + (kt) * 64 + lk4);                               \
    _Pragma("unroll")                                                           \
    for (int j = 0; j < 8; ++j) {                                               \
      const int m = mrow + 16 * j;                                              \
      float h0 = fminf(fmaxf(d[j] * ev.x, 0.f), 1.f);                           \
      float h1 = fminf(fmaxf(d[j] * ev.y, 0.f), 1.f);                           \
      float h2 = fminf(fmaxf(d[j] * ev.z, 0.f), 1.f);                           \
      float h3 = fminf(fmaxf(d[j] * ev.w, 0.f), 1.f);                           \
      uint2 pk;                                                                 \
      pk.x = packbf16(h0, h1);                                                  \
      pk.y = packbf16(h2, h3);                                                  \
      *(uint2*)(Ab + m * SAB + (lk4 ^ aswz)) = pk;                              \
    }                                                                           \
  }

#define MFMA_STEP(Ab, Bb)                                                       \
  {                                                                             \
    _Pragma("unroll")                                                           \
    for (int kk = 0; kk < 2; ++kk) {                                            \
      const int k0 = kk * 32 + quad * 8;                                        \
      s16x8 af[4], bfr[4];                                                      \
      _Pragma("unroll")                                                         \
      for (int i = 0; i < 4; ++i) {                                             \
        const int m = wm + i * 16 + ln16;                                       \
        af[i] = *(const s16x8*)(Ab + m * SAB + (k0 ^ ((m & 7) * 8)));           \
      }                                                                         \
      _Pragma("unroll")                                                         \
      for (int j = 0; j < 4; ++j) {                                             \
        const int n = wn + j * 16 + ln16;                                       \
        bfr[j] = *(const s16x8*)(Bb + n * SAB + (k0 ^ (((n >> 2) & 7) * 8)));   \
      }                                                                         \
      _Pragma("unroll")                                                         \
      for (int i = 0; i < 4; ++i)                                               \
        _Pragma("unroll")                                                       \
        for (int j = 0; j < 4; ++j)                                             \
          acc[i][j] = __builtin_amdgcn_mfma_f32_16x16x32_bf16(af[i], bfr[j], acc[i][j], 0, 0, 0); \
    }                                                                           \
  }

  ISSUE_B(pre0, 0);
  __syncthreads();   // eL visible

  for (int ch = 0; ch < nchunk; ++ch) {
    const bool do_sum = (ch == 0);
    // gather d for this chunk's rows (padding rows: d=0 -> h row = 0)
    float d[8];
#pragma unroll
    for (int j = 0; j < 8; ++j) {
      const int gi = ch * 128 + mrow + 16 * j;
      d[j] = 0.f;
      if (gi < nmid) {
        const int bb = listb[f * B_ + gi];
        d[j] = x[(size_t)bb * F_ + f] - bfv;
      }
    }

    fx4 acc[4][4];
#pragma unroll
    for (int i = 0; i < 4; ++i)
#pragma unroll
      for (int j = 0; j < 4; ++j)
        acc[i][j] = fx4{0.f, 0.f, 0.f, 0.f};

    for (int kt2 = 0; kt2 < 8; ++kt2) {
      const int kt = kt2 * 2;
      // even sub-step: buffer 0, consume pre0, prefetch pre1
      STAGE_A(kt, A0);
      PACK_B(pre0, B0, do_sum);
      ISSUE_B(pre1, kt + 1);
      __syncthreads();
      MFMA_STEP(A0, B0);
      // odd sub-step: buffer 1, consume pre1, prefetch pre0
      STAGE_A(kt + 1, A1);
      PACK_B(pre1, B1, do_sum);
      if (kt2 < 7) { ISSUE_B(pre0, kt + 2); }
      else if (ch + 1 < nchunk) { ISSUE_B(pre0, 0); }   // next chunk re-streams W1
      __syncthreads();
      MFMA_STEP(A1, B1);
    }

    // ---- epilogue ----
    // h2 = relu(acc + b1) -> H2 (over buf0 region; last MFMA read buf1 only)
#pragma unroll
    for (int j = 0; j < 4; ++j) {
      const int n = wn + j * 16 + ln16;
      const float b1v = b1[(size_t)f * V_ + nb * 128 + n];
#pragma unroll
      for (int i = 0; i < 4; ++i)
#pragma unroll
        for (int reg = 0; reg < 4; ++reg) {
          const int m = wm + i * 16 + quad * 4 + reg;   // C/D: row=(l>>4)*4+reg, col=l&15
          float v = fmaxf(acc[i][j][reg] + b1v, 0.f);
          H2[m * SH2 + n] = (unsigned short)bf16bits(v);
        }
    }
    __syncthreads();   // E1: all MFMA done; buf1 region now free

    // stage W2T (transposed, rows 10..15 zero) into A1 region
#pragma unroll
    for (int it = 0; it < 8; ++it) {
      const int idx = tid + it * 256;
      const int cc = idx & 15, v = idx >> 4;
      float val = (cc < C_) ? W2[((size_t)f * V_ + nb * 128 + v) * C_ + cc] : 0.f;
      W2T[cc * SH2 + v] = (unsigned short)bf16bits(val);
    }
    if (do_sum) {
      rsum[kq * 128 + n4 + 0] = csum[0];
      rsum[kq * 128 + n4 + 1] = csum[1];
      rsum[kq * 128 + n4 + 2] = csum[2];
      rsum[kq * 128 + n4 + 3] = csum[3];
    }
    __syncthreads();   // E2: H2, W2T, rsum visible

    // GEMM2: [128m x 128v] x [128v x 16c]
    fx4 acc2[4];
#pragma unroll
    for (int i = 0; i < 4; ++i) acc2[i] = fx4{0.f, 0.f, 0.f, 0.f};
#pragma unroll
    for (int kk = 0; kk < 2; ++kk) {
      const int k0 = wn + kk * 32 + quad * 8;
      s16x8 bfr = *(const s16x8*)(W2T + ln16 * SH2 + k0);
#pragma unroll
      for (int i = 0; i < 4; ++i) {
        const int m = wm + i * 16 + ln16;
        s16x8 afr = *(const s16x8*)(H2 + m * SH2 + k0);
        acc2[i] = __builtin_amdgcn_mfma_f32_16x16x32_bf16(afr, bfr, acc2[i], 0, 0, 0);
      }
    }

    // colsum finalize + zero/one table partials (fp32 W2), once per block
    if (do_sum && tid < 128) {
      float s = 0.f;
#pragma unroll
      for (int g = 0; g < 8; ++g) s += rsum[g * 128 + tid];
      const int v = nb * 128 + tid;
      colsum1[(size_t)f * V_ + v] = s;
      const float b1v = b1[(size_t)f * V_ + v];
      const float hz = fmaxf(b1v, 0.f);
      const float ho = fmaxf(s + b1v, 0.f);
      const float* w2p = W2 + ((size_t)f * V_ + v) * C_;
      float a0[C_], a1[C_];
#pragma unroll
      for (int cc = 0; cc < C_; ++cc) {
        const float wv = w2p[cc];
        a0[cc] = hz * wv;
        a1[cc] = ho * wv;
      }
#pragma unroll
      for (int off = 32; off > 0; off >>= 1)
#pragma unroll
        for (int cc = 0; cc < C_; ++cc) {
          a0[cc] += __shfl_down(a0[cc], off);
          a1[cc] += __shfl_down(a1[cc], off);
        }
      if ((tid & 63) == 0) {
        const int wv_ = tid >> 6;
#pragma unroll
        for (int cc = 0; cc < C_; ++cc) {
          redt[wv_ * 20 + cc] = a0[cc];
          redt[wv_ * 20 + C_ + cc] = a1[cc];
        }
      }
    }

    // middle-row logits
    if (ln16 < C_) {
#pragma unroll
      for (int i = 0; i < 4; ++i)
#pragma unroll
        for (int reg = 0; reg < 4; ++reg) {
          const int ml = wm + i * 16 + quad * 4 + reg;
          const int gm = ch * 128 + ml;
          if (gm < nmid) {
            const int bb = listb[f * B_ + gm];
            atomicAdd(logits_mid + (size_t)bb * C_ + ln16, acc2[i][reg]);
          }
        }
    }
    __syncthreads();   // E3: redt visible; LDS free for next chunk

    if (do_sum && tid < 20) {
      const float sv = redt[tid] + redt[20 + tid];
      if (tid < C_) atomicAdd(zlog + tid * F_ + f, sv);
      else          atomicAdd(olog + (tid - C_) * F_ + f, sv);
    }
  }
#undef ISSUE_B
#undef PACK_B
#undef STAGE_A
#undef MFMA_STEP
}

// ---------------- K4: gather per-row contributions + softmax ----------------
__global__ void nam_final(const float* __restrict__ x, const float* __restrict__ exu_b,
                          const float* __restrict__ emin,
                          const float* __restrict__ zlog, const float* __restrict__ olog,
                          const float* __restrict__ biasc, const float* __restrict__ logits_mid,
                          float* __restrict__ out)
{
  const int t = threadIdx.x;
  const int f = t & 127, sub = t >> 7;
  const int b = blockIdx.x * 2 + sub;
  const float d  = x[(size_t)b * F_ + f] - exu_b[f];
  const float em = emin[f];
  const bool is_zero = !(d > 0.f);
  const bool is_one  = (d > 0.f) && (d * em >= 1.f);
  float a[C_];
#pragma unroll
  for (int c = 0; c < C_; ++c) {
    const float zv = zlog[c * F_ + f];
    const float ov = olog[c * F_ + f];
    a[c] = is_zero ? zv : (is_one ? ov : 0.f);
  }
#pragma unroll
  for (int off = 32; off > 0; off >>= 1)
#pragma unroll
    for (int c = 0; c < C_; ++c) a[c] += __shfl_down(a[c], off);
  __shared__ float red[4][C_];
  __shared__ float lg[2][C_];
  const int wv_ = t >> 6, ln = t & 63;
  if (ln == 0)
#pragma unroll
    for (int c = 0; c < C_; ++c) red[wv_][c] = a[c];
  __syncthreads();
  if (t < 2 * C_) {
    const int rb = t / C_, c = t % C_;
    lg[rb][c] = red[rb * 2][c] + red[rb * 2 + 1][c]
              + logits_mid[(size_t)(blockIdx.x * 2 + rb) * C_ + c] + biasc[c];
  }
  __syncthreads();
  if (t < 2) {
    float mx = -3.0e38f;
#pragma unroll
    for (int c = 0; c < C_; ++c) mx = fmaxf(mx, lg[t][c]);
    float e[C_];
    float s = 0.f;
#pragma unroll
    for (int c = 0; c < C_; ++c) { e[c] = expf(lg[t][c] - mx); s += e[c]; }
    const float inv = 1.f / s;
#pragma unroll
    for (int c = 0; c < C_; ++c) out[(size_t)(blockIdx.x * 2 + t) * C_ + c] = e[c] * inv;
  }
}

extern "C" void kernel_launch(void* const* d_in, const int* in_sizes, int n_in,
                              void* d_out, int out_size, void* d_ws, size_t ws_size,
                              hipStream_t stream)
{
  const float* x     = (const float*)d_in[0];
  const float* exu_w = (const float*)d_in[1];
  const float* exu_b = (const float*)d_in[2];
  const float* W1    = (const float*)d_in[3];
  const float* b1    = (const float*)d_in[4];
  const float* W2    = (const float*)d_in[5];
  const float* b2    = (const float*)d_in[6];
  const float* b_out = (const float*)d_in[7];
  float* out = (float*)d_out;

  char* ws = (char*)d_ws;
  float* emin       = (float*)(ws + 0);                 //   512 B
  float* biasc      = (float*)(ws + 512);               //    40 B (pad to 576)
  int*   count      = (int*)  (ws + 576);               //   512 B
  int*   listb      = (int*)  (ws + 1088);              // 1 MB (128*2048*4)
  float* colsum1    = (float*)(ws + 1049664);           // 256 KB
  float* zlog       = (float*)(ws + 1311808);           //  5 KB
  float* olog       = (float*)(ws + 1316928);           //  5 KB
  float* logits_mid = (float*)(ws + 1322048);           // 80 KB -> ends 1403968

  nam_prep<<<F_ + 1 + (B_ * C_ / 256), 256, 0, stream>>>(exu_w, b2, b_out, emin, biasc,
                                                          count, logits_mid, zlog, olog);
  nam_classify<<<B_ / 2, 256, 0, stream>>>(x, exu_b, emin, count, listb);
  nam_mid<<<F_ * 4, 256, 0, stream>>>(x, exu_w, exu_b, W1, b1, W2, listb, count,
                                       colsum1, logits_mid, zlog, olog);
  nam_final<<<B_ / 2, 256, 0, stream>>>(x, exu_b, emin, zlog, olog, biasc, logits_mid, out);
}